// Round 16
// baseline (213.989 us; speedup 1.0000x reference)
//
#include <hip/hip_runtime.h>
#include <hip/hip_bf16.h>

typedef __attribute__((ext_vector_type(8))) short short8;
typedef __attribute__((ext_vector_type(4))) float f32x4;

#define NROW 8192
#define FDIM 64
#define INDIM 128
#define BM 128        // rows per k_main block (4 waves x 32 rows)
#define SPLITS 16
#define NPANEL (NROW / BM)  // 64
#define MBOUND 48.0f  // static softmax-shift bound (validated R3-R11)
#define L2E 1.44269504f

static __device__ __forceinline__ unsigned short bfb(float x) {
  __hip_bfloat16 b = __float2bfloat16(x);
  return *reinterpret_cast<unsigned short*>(&b);
}
static __device__ __forceinline__ float b2f(unsigned int u16) {
  unsigned int x = u16 << 16;
  float f;
  __builtin_memcpy(&f, &x, 4);
  return f;
}
static __device__ __forceinline__ float lrelu(float x) { return fmaxf(x, 0.01f * x); }

// ---------------- Kernel 1: Wh = h@W (f32), WhT (bf16, f-major), s = Wh@a1, d = Wh@a2 ------------
__global__ __launch_bounds__(256) void k_wh(const float* __restrict__ h,
                                            const float* __restrict__ W,
                                            const float* __restrict__ a,
                                            __hip_bfloat16* __restrict__ WhT,
                                            float* __restrict__ s,
                                            float* __restrict__ d) {
  const int i = blockIdx.x * 4 + (threadIdx.x >> 6);
  const int f = threadIdx.x & 63;
  const float* hrow = h + (size_t)i * INDIM;
  float acc = 0.f;
#pragma unroll 8
  for (int k = 0; k < INDIM; ++k) acc = fmaf(hrow[k], W[k * FDIM + f], acc);
  WhT[(size_t)f * NROW + i] = __float2bfloat16(acc);
  float p1 = acc * a[f];
  float p2 = acc * a[FDIM + f];
#pragma unroll
  for (int m = 32; m; m >>= 1) {
    p1 += __shfl_xor(p1, m, 64);
    p2 += __shfl_xor(p2, m, 64);
  }
  if (f == 0) { s[i] = p1; d[i] = p2; }
}

// ---------------- Kernel 2: fused masked-softmax-attention (R9 body + sc0 L1-bypass adj) ---------
// Coalesced adj dword loads with sc0 (L1 bypass, L2 cached) -> __ballot -> fragment bits.
// Barrier-free, LDS-free. Packed bf16 partials, 256 B-contiguous stores.
__global__ __launch_bounds__(256, 4) void k_main(const int* __restrict__ adj,
                                                 const __hip_bfloat16* __restrict__ WhT,
                                                 const float* __restrict__ sArr,
                                                 const float* __restrict__ dArr,
                                                 unsigned int* __restrict__ accp,
                                                 float* __restrict__ Zp) {
  const int t = threadIdx.x;
  const int w = t >> 6, l = t & 63;
  const int lr = l & 15;  // fragment row index
  const int lk = l >> 4;  // k-group 0..3
  const int panel = blockIdx.x / SPLITS;
  const int split = blockIdx.x - panel * SPLITS;
  const int row0 = panel * BM + w * 32;
  const int jspan = NROW / SPLITS;  // 512
  const int j0 = split * jspan;
  const int nchunk = jspan / 64;    // 8

  const float s0 = sArr[row0 + lr];
  const float s1 = sArr[row0 + 16 + lr];
  const float sm0 = -lrelu(s0 + MBOUND) * L2E;
  const float sm1 = -lrelu(s1 + MBOUND) * L2E;

  f32x4 acc[2][4];
#pragma unroll
  for (int ri = 0; ri < 2; ++ri)
#pragma unroll
    for (int nf = 0; nf < 4; ++nf) acc[ri][nf] = (f32x4){0.f, 0.f, 0.f, 0.f};
  float z0 = 0.f, z1 = 0.f;

  const int* adjp = adj + (size_t)row0 * NROW + j0 + l;  // lane l -> column j0+off+l
  const float* dp = dArr + j0 + lk * 8;
  const __hip_bfloat16* bbase = WhT + (size_t)lr * NROW + j0 + lk * 8;

  for (int c = 0; c < nchunk; ++c) {
    const int off = c * 64;

    // ---- coalesced sc0 adj loads -> 2 x 64-bit masks per lane (rows lr and lr+16) ----
    unsigned long long M0 = 0ull, M1 = 0ull;
    {
      int av0[16], av1[16];
#pragma unroll
      for (int r = 0; r < 16; ++r)
        asm volatile("global_load_dword %0, %1, off sc0"
                     : "=v"(av0[r])
                     : "v"(adjp + (size_t)r * NROW + off));
#pragma unroll
      for (int r = 0; r < 16; ++r)
        asm volatile("global_load_dword %0, %1, off sc0"
                     : "=v"(av1[r])
                     : "v"(adjp + (size_t)(16 + r) * NROW + off));
      asm volatile("s_waitcnt vmcnt(16)" ::: "memory");
      __builtin_amdgcn_sched_barrier(0);
#pragma unroll
      for (int r = 0; r < 16; ++r) {
        unsigned long long b = __ballot(av0[r] > 0);
        M0 = (lr == r) ? b : M0;
      }
      asm volatile("s_waitcnt vmcnt(0)" ::: "memory");
      __builtin_amdgcn_sched_barrier(0);
#pragma unroll
      for (int r = 0; r < 16; ++r) {
        unsigned long long b = __ballot(av1[r] > 0);
        M1 = (lr == r) ? b : M1;
      }
    }

#pragma unroll
    for (int ks = 0; ks < 2; ++ks) {
      const int jo = off + ks * 32;
      const unsigned int y0 = (unsigned int)(M0 >> (ks * 32 + lk * 8)) & 0xffu;
      const unsigned int y1 = (unsigned int)(M1 >> (ks * 32 + lk * 8)) & 0xffu;

      short8 b0 = *(const short8*)(bbase + jo);
      short8 b1 = *(const short8*)(bbase + jo + 16 * NROW);
      short8 b2 = *(const short8*)(bbase + jo + 32 * NROW);
      short8 b3 = *(const short8*)(bbase + jo + 48 * NROW);

      float dj[8];
      *(float4*)&dj[0] = *(const float4*)(dp + jo);
      *(float4*)&dj[4] = *(const float4*)(dp + jo + 4);

      short8 pa0, pa1;
#pragma unroll
      for (int q = 0; q < 8; ++q) {
        const float dq = dj[q];
        float e0 = exp2f(fmaf(lrelu(s0 + dq), L2E, sm0));
        float e1 = exp2f(fmaf(lrelu(s1 + dq), L2E, sm1));
        float w0 = ((y0 >> q) & 1u) ? e0 : 0.f;
        float w1 = ((y1 >> q) & 1u) ? e1 : 0.f;
        z0 += w0;
        z1 += w1;
        pa0[q] = (short)bfb(w0);
        pa1[q] = (short)bfb(w1);
      }

      acc[0][0] = __builtin_amdgcn_mfma_f32_16x16x32_bf16(pa0, b0, acc[0][0], 0, 0, 0);
      acc[0][1] = __builtin_amdgcn_mfma_f32_16x16x32_bf16(pa0, b1, acc[0][1], 0, 0, 0);
      acc[0][2] = __builtin_amdgcn_mfma_f32_16x16x32_bf16(pa0, b2, acc[0][2], 0, 0, 0);
      acc[0][3] = __builtin_amdgcn_mfma_f32_16x16x32_bf16(pa0, b3, acc[0][3], 0, 0, 0);
      acc[1][0] = __builtin_amdgcn_mfma_f32_16x16x32_bf16(pa1, b0, acc[1][0], 0, 0, 0);
      acc[1][1] = __builtin_amdgcn_mfma_f32_16x16x32_bf16(pa1, b1, acc[1][1], 0, 0, 0);
      acc[1][2] = __builtin_amdgcn_mfma_f32_16x16x32_bf16(pa1, b2, acc[1][2], 0, 0, 0);
      acc[1][3] = __builtin_amdgcn_mfma_f32_16x16x32_bf16(pa1, b3, acc[1][3], 0, 0, 0);
    }
  }

  // ---- Z partials: sum the 4 k-groups of each row ----
  z0 += __shfl_xor(z0, 16, 64);
  z0 += __shfl_xor(z0, 32, 64);
  z1 += __shfl_xor(z1, 16, 64);
  z1 += __shfl_xor(z1, 32, 64);
  if (l < 16) {
    Zp[(size_t)blockIdx.x * BM + w * 32 + lr] = z0;
    Zp[(size_t)blockIdx.x * BM + w * 32 + 16 + lr] = z1;
  }

  // ---- packed bf16 partial store, fully coalesced (256 B per instruction) ----
  unsigned int* ab = accp + (size_t)blockIdx.x * 4096 + w * 1024 + l;
#pragma unroll
  for (int ri = 0; ri < 2; ++ri)
#pragma unroll
    for (int nf = 0; nf < 4; ++nf)
#pragma unroll
      for (int qp = 0; qp < 2; ++qp) {
        unsigned int pv = (unsigned int)bfb(acc[ri][nf][2 * qp]) |
                          ((unsigned int)bfb(acc[ri][nf][2 * qp + 1]) << 16);
        ab[ri * 512 + nf * 128 + qp * 64] = pv;
      }
}

// ---------------- Kernel 3: combine partials, normalize, elu ----------------
__global__ __launch_bounds__(256) void k_combine(const unsigned int* __restrict__ accp,
                                                 const float* __restrict__ Zp,
                                                 float* __restrict__ out) {
  __shared__ float zsh[BM];
  const int panel = blockIdx.x >> 2;
  const int part = blockIdx.x & 3;
  const int t = threadIdx.x;

  if (t < BM) {
    float z = 0.f;
#pragma unroll
    for (int sp = 0; sp < SPLITS; ++sp)
      z += Zp[(size_t)(panel * SPLITS + sp) * BM + t];
    zsh[t] = z;
  }
  __syncthreads();

  const unsigned int* base = accp + (size_t)panel * SPLITS * 4096;
#pragma unroll
  for (int k = 0; k < 4; ++k) {
    const int D = part * 1024 + k * 256 + t;
    float sum0 = 0.f, sum1 = 0.f;
#pragma unroll
    for (int sp = 0; sp < SPLITS; ++sp) {
      unsigned int v = base[(size_t)sp * 4096 + D];
      sum0 += b2f(v & 0xffffu);
      sum1 += b2f(v >> 16);
    }
    const int w = D >> 10, ri = (D >> 9) & 1, nf = (D >> 7) & 3, qp = (D >> 6) & 1;
    const int lkD = (D >> 4) & 3, lrD = D & 15;
    const int row = w * 32 + ri * 16 + lkD * 4 + 2 * qp;
    const int col = nf * 16 + lrD;
    const float v0 = sum0 / zsh[row];
    const float v1 = sum1 / zsh[row + 1];
    out[(size_t)(panel * BM + row) * FDIM + col] = (v0 > 0.f) ? v0 : expm1f(v0);
    out[(size_t)(panel * BM + row + 1) * FDIM + col] = (v1 > 0.f) ? v1 : expm1f(v1);
  }
}

extern "C" void kernel_launch(void* const* d_in, const int* in_sizes, int n_in,
                              void* d_out, int out_size, void* d_ws, size_t ws_size,
                              hipStream_t stream) {
  const float* h = (const float*)d_in[0];
  const int* adj = (const int*)d_in[1];
  const float* W = (const float*)d_in[2];
  const float* a = (const float*)d_in[3];
  float* out = (float*)d_out;

  const int nblk = NPANEL * SPLITS;  // 1024

  char* p = (char*)d_ws;
  __hip_bfloat16* WhT = (__hip_bfloat16*)p;               // 1 MB
  float* s = (float*)(p + 1048576);                       // 32 KB
  float* d = (float*)(p + 1048576 + 32768);               // 32 KB
  float* Zp = (float*)(p + 1048576 + 65536);              // 512 KB
  unsigned int* accp =
      (unsigned int*)((char*)Zp + (size_t)nblk * BM * 4); // 16.8 MB

  hipLaunchKernelGGL(k_wh, dim3(NROW / 4), dim3(256), 0, stream, h, W, a, WhT, s, d);
  hipLaunchKernelGGL(k_main, dim3(nblk), dim3(256), 0, stream, adj, WhT, s, d, accp, Zp);
  hipLaunchKernelGGL(k_combine, dim3(NPANEL * 4), dim3(256), 0, stream, accp, Zp, out);
}

// Round 17
// 100.429 us; speedup vs baseline: 2.1308x; 2.1308x over previous
//
#include <hip/hip_runtime.h>
#include <hip/hip_bf16.h>

typedef __attribute__((ext_vector_type(8))) short short8;
typedef __attribute__((ext_vector_type(4))) float f32x4;

#define NROW 8192
#define FDIM 64
#define INDIM 128
#define BM 128        // rows per k_main block (4 waves x 32 rows)
#define SPLITS 16
#define NPANEL (NROW / BM)  // 64
#define MBOUND 48.0f  // static softmax-shift bound (validated R3-R16)
#define L2E 1.44269504f

static __device__ __forceinline__ unsigned short bfb(float x) {
  __hip_bfloat16 b = __float2bfloat16(x);
  return *reinterpret_cast<unsigned short*>(&b);
}
static __device__ __forceinline__ float b2f(unsigned int u16) {
  unsigned int x = u16 << 16;
  float f;
  __builtin_memcpy(&f, &x, 4);
  return f;
}
static __device__ __forceinline__ float lrelu(float x) { return fmaxf(x, 0.01f * x); }

// ---------------- Kernel 1: Wh = h@W (f32), WhT (bf16, f-major), s = Wh@a1, d = Wh@a2 ------------
__global__ __launch_bounds__(256) void k_wh(const float* __restrict__ h,
                                            const float* __restrict__ W,
                                            const float* __restrict__ a,
                                            __hip_bfloat16* __restrict__ WhT,
                                            float* __restrict__ s,
                                            float* __restrict__ d) {
  const int i = blockIdx.x * 4 + (threadIdx.x >> 6);
  const int f = threadIdx.x & 63;
  const float* hrow = h + (size_t)i * INDIM;
  float acc = 0.f;
#pragma unroll 8
  for (int k = 0; k < INDIM; ++k) acc = fmaf(hrow[k], W[k * FDIM + f], acc);
  WhT[(size_t)f * NROW + i] = __float2bfloat16(acc);
  float p1 = acc * a[f];
  float p2 = acc * a[FDIM + f];
#pragma unroll
  for (int m = 32; m; m >>= 1) {
    p1 += __shfl_xor(p1, m, 64);
    p2 += __shfl_xor(p2, m, 64);
  }
  if (f == 0) { s[i] = p1; d[i] = p2; }
}

// ---------------- Kernel 2: fused masked-softmax-attention (R9-proven body) ----------------------
// Coalesced plain adj dword loads -> __ballot -> per-lane fragment bits. Barrier-free, LDS-free,
// compiler-scheduled loads (no explicit waitcnt drains — probes showed any drain serializes).
// Partials: 2x bf16 packed per dword at flat offset -> every store is 256 B contiguous.
__global__ __launch_bounds__(256, 4) void k_main(const int* __restrict__ adj,
                                                 const __hip_bfloat16* __restrict__ WhT,
                                                 const float* __restrict__ sArr,
                                                 const float* __restrict__ dArr,
                                                 unsigned int* __restrict__ accp,
                                                 float* __restrict__ Zp) {
  const int t = threadIdx.x;
  const int w = t >> 6, l = t & 63;
  const int lr = l & 15;  // fragment row index
  const int lk = l >> 4;  // k-group 0..3
  const int panel = blockIdx.x / SPLITS;
  const int split = blockIdx.x - panel * SPLITS;
  const int row0 = panel * BM + w * 32;
  const int jspan = NROW / SPLITS;  // 512
  const int j0 = split * jspan;
  const int nchunk = jspan / 64;    // 8

  const float s0 = sArr[row0 + lr];
  const float s1 = sArr[row0 + 16 + lr];
  const float sm0 = -lrelu(s0 + MBOUND) * L2E;
  const float sm1 = -lrelu(s1 + MBOUND) * L2E;

  f32x4 acc[2][4];
#pragma unroll
  for (int ri = 0; ri < 2; ++ri)
#pragma unroll
    for (int nf = 0; nf < 4; ++nf) acc[ri][nf] = (f32x4){0.f, 0.f, 0.f, 0.f};
  float z0 = 0.f, z1 = 0.f;

  const int* adjp = adj + (size_t)row0 * NROW + j0 + l;  // lane l -> column j0+off+l
  const float* dp = dArr + j0 + lk * 8;
  const __hip_bfloat16* bbase = WhT + (size_t)lr * NROW + j0 + lk * 8;

  for (int c = 0; c < nchunk; ++c) {
    const int off = c * 64;

    // ---- coalesced adj -> 2 x 64-bit masks per lane (rows lr and lr+16) ----
    unsigned long long M0 = 0ull, M1 = 0ull;
    {
      int av[16];
#pragma unroll
      for (int r = 0; r < 16; ++r) av[r] = adjp[(size_t)r * NROW + off];
#pragma unroll
      for (int r = 0; r < 16; ++r) {
        unsigned long long b = __ballot(av[r] > 0);
        M0 = (lr == r) ? b : M0;
      }
#pragma unroll
      for (int r = 0; r < 16; ++r) av[r] = adjp[(size_t)(16 + r) * NROW + off];
#pragma unroll
      for (int r = 0; r < 16; ++r) {
        unsigned long long b = __ballot(av[r] > 0);
        M1 = (lr == r) ? b : M1;
      }
    }

#pragma unroll
    for (int ks = 0; ks < 2; ++ks) {
      const int jo = off + ks * 32;
      const unsigned int y0 = (unsigned int)(M0 >> (ks * 32 + lk * 8)) & 0xffu;
      const unsigned int y1 = (unsigned int)(M1 >> (ks * 32 + lk * 8)) & 0xffu;

      short8 b0 = *(const short8*)(bbase + jo);
      short8 b1 = *(const short8*)(bbase + jo + 16 * NROW);
      short8 b2 = *(const short8*)(bbase + jo + 32 * NROW);
      short8 b3 = *(const short8*)(bbase + jo + 48 * NROW);

      float dj[8];
      *(float4*)&dj[0] = *(const float4*)(dp + jo);
      *(float4*)&dj[4] = *(const float4*)(dp + jo + 4);

      short8 pa0, pa1;
#pragma unroll
      for (int q = 0; q < 8; ++q) {
        const float dq = dj[q];
        float e0 = exp2f(fmaf(lrelu(s0 + dq), L2E, sm0));
        float e1 = exp2f(fmaf(lrelu(s1 + dq), L2E, sm1));
        float w0 = ((y0 >> q) & 1u) ? e0 : 0.f;
        float w1 = ((y1 >> q) & 1u) ? e1 : 0.f;
        z0 += w0;
        z1 += w1;
        pa0[q] = (short)bfb(w0);
        pa1[q] = (short)bfb(w1);
      }

      acc[0][0] = __builtin_amdgcn_mfma_f32_16x16x32_bf16(pa0, b0, acc[0][0], 0, 0, 0);
      acc[0][1] = __builtin_amdgcn_mfma_f32_16x16x32_bf16(pa0, b1, acc[0][1], 0, 0, 0);
      acc[0][2] = __builtin_amdgcn_mfma_f32_16x16x32_bf16(pa0, b2, acc[0][2], 0, 0, 0);
      acc[0][3] = __builtin_amdgcn_mfma_f32_16x16x32_bf16(pa0, b3, acc[0][3], 0, 0, 0);
      acc[1][0] = __builtin_amdgcn_mfma_f32_16x16x32_bf16(pa1, b0, acc[1][0], 0, 0, 0);
      acc[1][1] = __builtin_amdgcn_mfma_f32_16x16x32_bf16(pa1, b1, acc[1][1], 0, 0, 0);
      acc[1][2] = __builtin_amdgcn_mfma_f32_16x16x32_bf16(pa1, b2, acc[1][2], 0, 0, 0);
      acc[1][3] = __builtin_amdgcn_mfma_f32_16x16x32_bf16(pa1, b3, acc[1][3], 0, 0, 0);
    }
  }

  // ---- Z partials: sum the 4 k-groups of each row ----
  z0 += __shfl_xor(z0, 16, 64);
  z0 += __shfl_xor(z0, 32, 64);
  z1 += __shfl_xor(z1, 16, 64);
  z1 += __shfl_xor(z1, 32, 64);
  if (l < 16) {
    Zp[(size_t)blockIdx.x * BM + w * 32 + lr] = z0;
    Zp[(size_t)blockIdx.x * BM + w * 32 + 16 + lr] = z1;
  }

  // ---- packed bf16 partial store, fully coalesced (256 B per instruction) ----
  // dword D = w*1024 + ri*512 + nf*128 + qp*64 + l ; low16 = q=2qp, high16 = q=2qp+1
  unsigned int* ab = accp + (size_t)blockIdx.x * 4096 + w * 1024 + l;
#pragma unroll
  for (int ri = 0; ri < 2; ++ri)
#pragma unroll
    for (int nf = 0; nf < 4; ++nf)
#pragma unroll
      for (int qp = 0; qp < 2; ++qp) {
        unsigned int pv = (unsigned int)bfb(acc[ri][nf][2 * qp]) |
                          ((unsigned int)bfb(acc[ri][nf][2 * qp + 1]) << 16);
        ab[ri * 512 + nf * 128 + qp * 64] = pv;
      }
}

// ---------------- Kernel 3: combine partials, normalize, elu ----------------
__global__ __launch_bounds__(256) void k_combine(const unsigned int* __restrict__ accp,
                                                 const float* __restrict__ Zp,
                                                 float* __restrict__ out) {
  __shared__ float zsh[BM];
  const int panel = blockIdx.x >> 2;
  const int part = blockIdx.x & 3;
  const int t = threadIdx.x;

  if (t < BM) {
    float z = 0.f;
#pragma unroll
    for (int sp = 0; sp < SPLITS; ++sp)
      z += Zp[(size_t)(panel * SPLITS + sp) * BM + t];
    zsh[t] = z;
  }
  __syncthreads();

  const unsigned int* base = accp + (size_t)panel * SPLITS * 4096;
#pragma unroll
  for (int k = 0; k < 4; ++k) {
    const int D = part * 1024 + k * 256 + t;
    float sum0 = 0.f, sum1 = 0.f;
#pragma unroll
    for (int sp = 0; sp < SPLITS; ++sp) {
      unsigned int v = base[(size_t)sp * 4096 + D];
      sum0 += b2f(v & 0xffffu);
      sum1 += b2f(v >> 16);
    }
    const int w = D >> 10, ri = (D >> 9) & 1, nf = (D >> 7) & 3, qp = (D >> 6) & 1;
    const int lkD = (D >> 4) & 3, lrD = D & 15;
    const int row = w * 32 + ri * 16 + lkD * 4 + 2 * qp;
    const int col = nf * 16 + lrD;
    const float v0 = sum0 / zsh[row];
    const float v1 = sum1 / zsh[row + 1];
    out[(size_t)(panel * BM + row) * FDIM + col] = (v0 > 0.f) ? v0 : expm1f(v0);
    out[(size_t)(panel * BM + row + 1) * FDIM + col] = (v1 > 0.f) ? v1 : expm1f(v1);
  }
}

extern "C" void kernel_launch(void* const* d_in, const int* in_sizes, int n_in,
                              void* d_out, int out_size, void* d_ws, size_t ws_size,
                              hipStream_t stream) {
  const float* h = (const float*)d_in[0];
  const int* adj = (const int*)d_in[1];
  const float* W = (const float*)d_in[2];
  const float* a = (const float*)d_in[3];
  float* out = (float*)d_out;

  const int nblk = NPANEL * SPLITS;  // 1024

  char* p = (char*)d_ws;
  __hip_bfloat16* WhT = (__hip_bfloat16*)p;               // 1 MB
  float* s = (float*)(p + 1048576);                       // 32 KB
  float* d = (float*)(p + 1048576 + 32768);               // 32 KB
  float* Zp = (float*)(p + 1048576 + 65536);              // 512 KB
  unsigned int* accp =
      (unsigned int*)((char*)Zp + (size_t)nblk * BM * 4); // 16.8 MB

  hipLaunchKernelGGL(k_wh, dim3(NROW / 4), dim3(256), 0, stream, h, W, a, WhT, s, d);
  hipLaunchKernelGGL(k_main, dim3(nblk), dim3(256), 0, stream, adj, WhT, s, d, accp, Zp);
  hipLaunchKernelGGL(k_combine, dim3(NPANEL * 4), dim3(256), 0, stream, accp, Zp, out);
}